// Round 1
// baseline (2516.458 us; speedup 1.0000x reference)
//
#include <hip/hip_runtime.h>
#include <math.h>

#define NB   4
#define NBOX 512
#define CI   128
#define HH   376
#define WW   376
#define OC   28

#define TBY  8
#define TBX  16
#define CICH 8
#define XLP  132   // padded LDS stride for epilogue x-tile

// ---------------- prep: repack w1 to [ci][tap][co], fold BN ----------------
__global__ void __launch_bounds__(256)
prep_kernel(const float* __restrict__ w1, const float* __restrict__ gamma,
            const float* __restrict__ beta, const float* __restrict__ rmean,
            const float* __restrict__ rvar, float* __restrict__ w1p,
            float* __restrict__ bnsc, float* __restrict__ bnsh)
{
    int idx = blockIdx.x * 256 + threadIdx.x;
    if (idx < CI * CI * 9) {
        int ci  = idx / (9 * CI);
        int rem = idx - ci * 9 * CI;
        int tap = rem / CI;
        int co  = rem - tap * CI;
        w1p[idx] = w1[(co * CI + ci) * 9 + tap];
    }
    if (idx < CI) {
        float rs = rsqrtf(rvar[idx] + 1e-3f);
        bnsc[idx] = gamma[idx] * rs;
        bnsh[idx] = beta[idx] - rmean[idx] * gamma[idx] * rs;
    }
}

// ---------------- fused 3x3 conv + BN + ReLU + 1x1 conv ----------------
// block: 256 threads, tile 8 rows x 16 cols x all 128 out-ch.
// thread: 4 pixels x 16 out-ch accumulators.
__global__ void __launch_bounds__(256, 3)
conv_fused(const float* __restrict__ feat, const float* __restrict__ w1p,
           const float* __restrict__ bnsc, const float* __restrict__ bnsh,
           const float* __restrict__ w2, float* __restrict__ confi)
{
    __shared__ float smem[1440 + 9216];   // 42.6 KB
    float* fl = smem;                     // [8 ci][10 rows][18 cols]
    float* wl = smem + 1440;              // [8 ci][9 tap][128 co]
    float* xl = smem;                     // epilogue union: [64 px][132]

    const int tid = threadIdx.x;
    const int cog = tid >> 5;     // 0..7  -> out-ch group of 16
    const int pg  = tid & 31;
    const int pr  = pg >> 4;      // 0..1
    const int pc  = pg & 15;      // 0..15
    const int x0  = blockIdx.x * TBX;
    const int y0  = blockIdx.y * TBY;
    const int b   = blockIdx.z;

    float acc[4][16];
#pragma unroll
    for (int i = 0; i < 4; ++i)
#pragma unroll
        for (int j = 0; j < 16; ++j) acc[i][j] = 0.f;

    const float* featb = feat + (size_t)b * CI * HH * WW;

    for (int ci0 = 0; ci0 < CI; ci0 += CICH) {
        __syncthreads();
        // stage feat tile (with halo, zero-padded)
        for (int e = tid; e < CICH * 180; e += 256) {
            int ci  = e / 180;
            int rem = e - ci * 180;
            int ry  = rem / 18;
            int rx  = rem - ry * 18;
            int gy  = y0 + ry - 1;
            int gx  = x0 + rx - 1;
            float v = 0.f;
            if ((unsigned)gy < HH && (unsigned)gx < WW)
                v = featb[((size_t)(ci0 + ci) * HH + gy) * WW + gx];
            fl[e] = v;
        }
        // stage weights (linear, coalesced float4)
        {
            const float4* src = (const float4*)(w1p + (size_t)ci0 * 9 * CI);
            float4* dst = (float4*)wl;
            for (int e = tid; e < CICH * 9 * CI / 4; e += 256) dst[e] = src[e];
        }
        __syncthreads();

        for (int ci = 0; ci < CICH; ++ci) {
            const float* flc = fl + ci * 180 + pr * 18 + pc;
            const float* wlc = wl + ci * 9 * CI + cog * 16;
#pragma unroll
            for (int tap = 0; tap < 9; ++tap) {
                const int dy = tap / 3, dx = tap % 3;
                float a0 = flc[(0 + dy) * 18 + dx];
                float a1 = flc[(2 + dy) * 18 + dx];
                float a2 = flc[(4 + dy) * 18 + dx];
                float a3 = flc[(6 + dy) * 18 + dx];
                const float4* wv = (const float4*)(wlc + tap * CI);
#pragma unroll
                for (int q = 0; q < 4; ++q) {
                    float4 w4 = wv[q];
                    acc[0][4*q+0] += a0 * w4.x; acc[0][4*q+1] += a0 * w4.y;
                    acc[0][4*q+2] += a0 * w4.z; acc[0][4*q+3] += a0 * w4.w;
                    acc[1][4*q+0] += a1 * w4.x; acc[1][4*q+1] += a1 * w4.y;
                    acc[1][4*q+2] += a1 * w4.z; acc[1][4*q+3] += a1 * w4.w;
                    acc[2][4*q+0] += a2 * w4.x; acc[2][4*q+1] += a2 * w4.y;
                    acc[2][4*q+2] += a2 * w4.z; acc[2][4*q+3] += a2 * w4.w;
                    acc[3][4*q+0] += a3 * w4.x; acc[3][4*q+1] += a3 * w4.y;
                    acc[3][4*q+2] += a3 * w4.z; acc[3][4*q+3] += a3 * w4.w;
                }
            }
        }
    }

    // BN + ReLU in place
#pragma unroll
    for (int j = 0; j < 16; ++j) {
        float sc = bnsc[cog * 16 + j];
        float sh = bnsh[cog * 16 + j];
#pragma unroll
        for (int i = 0; i < 4; ++i)
            acc[i][j] = fmaxf(acc[i][j] * sc + sh, 0.f);
    }

    // epilogue: two 64-pixel halves; x -> LDS, then 1x1 conv with w2
#pragma unroll
    for (int h = 0; h < 2; ++h) {
        __syncthreads();
#pragma unroll
        for (int i2 = 0; i2 < 2; ++i2) {
            int i  = 2 * h + i2;
            int r  = pr + 2 * i;            // local row 0..7
            int pl = (r - 4 * h) * 16 + pc; // 0..63
            float4* dst = (float4*)(xl + pl * XLP + cog * 16);
            dst[0] = make_float4(acc[i][0],  acc[i][1],  acc[i][2],  acc[i][3]);
            dst[1] = make_float4(acc[i][4],  acc[i][5],  acc[i][6],  acc[i][7]);
            dst[2] = make_float4(acc[i][8],  acc[i][9],  acc[i][10], acc[i][11]);
            dst[3] = make_float4(acc[i][12], acc[i][13], acc[i][14], acc[i][15]);
        }
        __syncthreads();
#pragma unroll
        for (int s = 0; s < 7; ++s) {
            int v  = tid + 256 * s;   // 1792 = 64 px * 28 oc
            int px = v & 63;
            int o  = v >> 6;
            const float4* xr = (const float4*)(xl + px * XLP);
            const float4* wr = (const float4*)(w2 + o * CI);
            float dot = 0.f;
#pragma unroll
            for (int q = 0; q < 32; ++q) {
                float4 xq = xr[q], wq = wr[q];
                dot += xq.x * wq.x + xq.y * wq.y + xq.z * wq.z + xq.w * wq.w;
            }
            int rr = 4 * h + (px >> 4);
            int cc = px & 15;
            int gy = y0 + rr;             // always < HH (47 exact y tiles)
            int gx = x0 + cc;
            if (gx < WW)
                confi[(((size_t)b * OC + o) * HH + gy) * WW + gx] = dot;
        }
    }
}

// ---------------- rotated-grid bilinear sampling + mean + sigmoid ----------------
__global__ void __launch_bounds__(256)
sample_kernel(const float* __restrict__ confi, const float* __restrict__ boxes,
              float* __restrict__ out)
{
    const int tid = threadIdx.x;
    const int lb  = tid >> 5;          // 8 boxes per block
    const int k   = tid & 31;          // part index (active k<28)
    const int box = blockIdx.x * 8 + lb;
    const int b   = box >> 9;
    const int n   = box & 511;

    const float* b5 = boxes + ((size_t)b * NBOX + n) * 5;
    float xg = b5[0], yg = b5[1], wg = b5[2], lg = b5[3], rg = b5[4];
    float cr = cosf(rg), sr = sinf(rg);

    float samp = 0.f;
    if (k < OC) {
        int i = k / 7, j = k - 7 * i;
        float xx = (-0.5f + (float)i * (1.0f / 3.0f)) * wg;
        float yy = (-0.5f + (float)j * (1.0f / 6.0f)) * lg;
        float px = xx * cr + yy * sr + xg;
        float py = yy * cr - xx * sr + yg;
        float fx = px * ((float)WW / (float)(WW - 1)) - 0.5f;
        float fy = py * ((float)HH / (float)(HH - 1)) - 0.5f;
        float x0f = floorf(fx), y0f = floorf(fy);
        float wx = fx - x0f, wy = fy - y0f;
        int xi = (int)x0f, yi = (int)y0f;
        const float* ch = confi + ((size_t)b * OC + k) * HH * WW;

        float v00 = 0.f, v10 = 0.f, v01 = 0.f, v11 = 0.f;
        bool okx0 = (xi >= 0)     && (xi <= WW - 1);
        bool okx1 = (xi + 1 >= 0) && (xi + 1 <= WW - 1);
        bool oky0 = (yi >= 0)     && (yi <= HH - 1);
        bool oky1 = (yi + 1 >= 0) && (yi + 1 <= HH - 1);
        if (okx0 && oky0) v00 = ch[(size_t)yi * WW + xi];
        if (okx1 && oky0) v10 = ch[(size_t)yi * WW + xi + 1];
        if (okx0 && oky1) v01 = ch[(size_t)(yi + 1) * WW + xi];
        if (okx1 && oky1) v11 = ch[(size_t)(yi + 1) * WW + xi + 1];
        samp = v00 * (1.f - wx) * (1.f - wy) + v10 * wx * (1.f - wy)
             + v01 * (1.f - wx) * wy         + v11 * wx * wy;
    }
    // reduce over the 32-lane group (xor masks < 32 stay in-group)
#pragma unroll
    for (int m = 16; m >= 1; m >>= 1) samp += __shfl_xor(samp, m, 64);

    if (k == 0) {
        float conf = samp * (1.0f / (float)OC);
        out[box] = 1.f / (1.f + expf(-conf));
    }
}

// ---------------- launch ----------------
extern "C" void kernel_launch(void* const* d_in, const int* in_sizes, int n_in,
                              void* d_out, int out_size, void* d_ws, size_t ws_size,
                              hipStream_t stream)
{
    const float* feat  = (const float*)d_in[0];
    const float* w1    = (const float*)d_in[1];
    const float* gamma = (const float*)d_in[2];
    const float* beta  = (const float*)d_in[3];
    const float* rmean = (const float*)d_in[4];
    const float* rvar  = (const float*)d_in[5];
    const float* w2    = (const float*)d_in[6];
    const float* boxes = (const float*)d_in[7];
    float* out = (float*)d_out;

    float* confi = (float*)d_ws;                          // 4*28*376*376 f32
    float* w1p   = confi + (size_t)NB * OC * HH * WW;     // 128*128*9 f32
    float* bnsc  = w1p + CI * CI * 9;
    float* bnsh  = bnsc + CI;

    prep_kernel<<<(CI * CI * 9 + 255) / 256, 256, 0, stream>>>(
        w1, gamma, beta, rmean, rvar, w1p, bnsc, bnsh);

    dim3 grid((WW + TBX - 1) / TBX, HH / TBY, NB);        // 24 x 47 x 4
    conv_fused<<<grid, 256, 0, stream>>>(feat, w1p, bnsc, bnsh, w2, confi);

    sample_kernel<<<NB * NBOX / 8, 256, 0, stream>>>(confi, boxes, out);
}

// Round 2
// 380.597 us; speedup vs baseline: 6.6119x; 6.6119x over previous
//
#include <hip/hip_runtime.h>
#include <math.h>

#define NB   4
#define NBOX 512
#define CI   128
#define HH   376
#define WW   376
#define OC   28
#define TS   16
#define TW   18

typedef short short8 __attribute__((ext_vector_type(8)));
typedef __bf16 bf16x8 __attribute__((ext_vector_type(8)));
typedef float f32x4 __attribute__((ext_vector_type(4)));

__device__ inline unsigned short f2bf(float f) {
    unsigned u = __builtin_bit_cast(unsigned, f);
    u = u + 0x7fffu + ((u >> 16) & 1u);   // RNE
    return (unsigned short)(u >> 16);
}

__device__ inline f32x4 mfma16(short8 a, short8 b, f32x4 c) {
    return __builtin_amdgcn_mfma_f32_16x16x32_bf16(
        __builtin_bit_cast(bf16x8, a), __builtin_bit_cast(bf16x8, b), c, 0, 0, 0);
}

// ---------------- prep: w1 -> [chunk][co][tap][ci_loc] bf16, w2 -> [32][128] bf16, BN fold ----
__global__ void __launch_bounds__(256)
prep_kernel(const float* __restrict__ w1, const float* __restrict__ gamma,
            const float* __restrict__ beta, const float* __restrict__ rmean,
            const float* __restrict__ rvar, const float* __restrict__ w2,
            unsigned short* __restrict__ w1p, unsigned short* __restrict__ w2p,
            float* __restrict__ bnsc, float* __restrict__ bnsh)
{
    int idx = blockIdx.x * 256 + threadIdx.x;
    if (idx < 4 * 128 * 9 * 32) {
        int cil = idx & 31;
        int t   = idx >> 5;
        int tap = t % 9;  t /= 9;
        int co  = t & 127;
        int chk = t >> 7;
        int ci  = chk * 32 + cil;
        w1p[idx] = f2bf(w1[((size_t)co * CI + ci) * 9 + tap]);
    }
    if (idx < 32 * 128) {
        int o = idx >> 7, k = idx & 127;
        w2p[idx] = (o < OC) ? f2bf(w2[o * CI + k]) : (unsigned short)0;
    }
    if (idx < CI) {
        float rs = rsqrtf(rvar[idx] + 1e-3f);
        bnsc[idx] = gamma[idx] * rs;
        bnsh[idx] = beta[idx] - rmean[idx] * gamma[idx] * rs;
    }
}

// ---------------- fused MFMA conv: 3x3 conv + BN + ReLU + 1x1 conv ----------------
// block = 512 thr (8 waves), tile 16x16 px x 128 co. Wave w owns output rows {2w, 2w+1}.
#define COMPUTE_HALF(H)                                                         \
    {                                                                           \
        _Pragma("unroll")                                                       \
        for (int tap = 0; tap < 9; ++tap) {                                     \
            const int dy = tap / 3, dx = tap - 3 * (tap / 3);                   \
            short8 bfr[4], afr[2];                                              \
            _Pragma("unroll")                                                   \
            for (int nf = 0; nf < 4; ++nf)                                      \
                bfr[nf] = *(const short8*)(wl + (nf * 16 + c) * 288 + tap * 32 + g * 8); \
            _Pragma("unroll")                                                   \
            for (int mf = 0; mf < 2; ++mf) {                                    \
                int pxi = (2 * wid + mf + dy) * TW + c + dx;                    \
                int sl  = g ^ ((pxi >> 1) & 3);                                 \
                afr[mf] = *(const short8*)(featl + pxi * 32 + sl * 8);          \
            }                                                                   \
            _Pragma("unroll")                                                   \
            for (int mf = 0; mf < 2; ++mf)                                      \
                _Pragma("unroll")                                               \
                for (int nf = 0; nf < 4; ++nf)                                  \
                    acc[H][mf][nf] = mfma16(afr[mf], bfr[nf], acc[H][mf][nf]);  \
        }                                                                       \
    }

__global__ void __launch_bounds__(512, 2)
conv_mfma(const float* __restrict__ feat, const unsigned short* __restrict__ w1p,
          const float* __restrict__ bnsc, const float* __restrict__ bnsh,
          const unsigned short* __restrict__ w2p, float* __restrict__ confi)
{
    __shared__ short sm[32768];            // 64 KB
    short* featl = sm;                     // conv phase: [324 px][32 ci] swizzled (20736 B)
    short* wl    = sm + 10368;             // conv phase: [64 co][288 k]     (36864 B)
    short* xt    = sm;                     // epilogue:   [256 px][128 co] swizzled (64 KB)

    const int tid  = threadIdx.x;
    const int wid  = tid >> 6;
    const int lane = tid & 63;
    const int c    = lane & 15;
    const int g    = lane >> 4;
    const int x0   = blockIdx.x * TS;
    const int y0   = blockIdx.y * TS;
    const int b    = blockIdx.z;

    f32x4 acc[2][2][4];
#pragma unroll
    for (int h = 0; h < 2; ++h)
#pragma unroll
        for (int m = 0; m < 2; ++m)
#pragma unroll
            for (int n = 0; n < 4; ++n)
                acc[h][m][n] = (f32x4){0.f, 0.f, 0.f, 0.f};

    for (int ch = 0; ch < 4; ++ch) {
        __syncthreads();
        // ---- stage feat chunk: [18][18] halo x 32 ci, pixel-major bf16, slot-swizzled
#pragma unroll
        for (int it = 0; it < 3; ++it) {
            int task = tid + it * 512;
            if (task < 1296) {                       // 324 px * 4 ci-groups
                int px  = task >> 2, cg = task & 3;
                int row = px / TW;
                int col = px - row * TW;
                int gy  = y0 + row - 1, gx = x0 + col - 1;
                bool ok = (unsigned)gy < HH && (unsigned)gx < WW;
                const float* p = feat +
                    (((size_t)(b * CI + ch * 32 + cg * 8)) * HH + gy) * WW + gx;
                short8 hv;
#pragma unroll
                for (int j = 0; j < 8; ++j) {
                    float v = ok ? p[(size_t)j * HH * WW] : 0.f;
                    hv[j] = (short)f2bf(v);
                }
                int slot = cg ^ ((px >> 1) & 3);
                *(short8*)(featl + px * 32 + slot * 8) = hv;
            }
        }
        // ---- stage weights half 0 (co 0..63), linear copy
        const short8* ws0 = (const short8*)(w1p + (size_t)ch * 128 * 288);
        for (int i = tid; i < 2304; i += 512) ((short8*)wl)[i] = ws0[i];
        __syncthreads();

        COMPUTE_HALF(0)

        __syncthreads();
        // ---- stage weights half 1 (co 64..127)
        const short8* ws1 = (const short8*)(w1p + (size_t)ch * 128 * 288 + 64 * 288);
        for (int i = tid; i < 2304; i += 512) ((short8*)wl)[i] = ws1[i];
        __syncthreads();

        COMPUTE_HALF(1)
    }

    // ---- w2 B-frags from global into regs; BN scale/shift
    short8 b2[2][4];
#pragma unroll
    for (int nf2 = 0; nf2 < 2; ++nf2)
#pragma unroll
        for (int kf = 0; kf < 4; ++kf)
            b2[nf2][kf] = *(const short8*)(w2p + (nf2 * 16 + c) * 128 + kf * 32 + g * 8);

    float sc[2][4], sh[2][4];
#pragma unroll
    for (int h = 0; h < 2; ++h)
#pragma unroll
        for (int nf = 0; nf < 4; ++nf) {
            int co = h * 64 + nf * 16 + c;
            sc[h][nf] = bnsc[co];
            sh[h][nf] = bnsh[co];
        }

    __syncthreads();   // conv reads of featl/wl done; safe to overwrite with xt

    // ---- BN + ReLU + write xt [px][co] bf16, 4-bit slot swizzle
#pragma unroll
    for (int h = 0; h < 2; ++h)
#pragma unroll
        for (int mf = 0; mf < 2; ++mf)
#pragma unroll
            for (int nf = 0; nf < 4; ++nf)
#pragma unroll
                for (int r = 0; r < 4; ++r) {
                    float v = fmaxf(acc[h][mf][nf][r] * sc[h][nf] + sh[h][nf], 0.f);
                    int px = (2 * wid + mf) * 16 + g * 4 + r;
                    int co = h * 64 + nf * 16 + c;
                    int s  = (co >> 3) ^ ((px >> 2) & 15) ^ ((px & 3) << 2);
                    xt[px * 128 + s * 8 + (co & 7)] = (short)f2bf(v);
                }
    __syncthreads();

    // ---- 1x1 conv via MFMA: M=256 px, N=32 (o padded), K=128
    f32x4 a2[2][2];
#pragma unroll
    for (int m = 0; m < 2; ++m)
#pragma unroll
        for (int n = 0; n < 2; ++n)
            a2[m][n] = (f32x4){0.f, 0.f, 0.f, 0.f};

#pragma unroll
    for (int mf2 = 0; mf2 < 2; ++mf2) {
        int px  = (2 * wid + mf2) * 16 + c;
        int swz = ((px >> 2) & 15) ^ ((px & 3) << 2);
#pragma unroll
        for (int kf = 0; kf < 4; ++kf) {
            int s = (kf * 4 + g) ^ swz;
            short8 a = *(const short8*)(xt + px * 128 + s * 8);
            a2[mf2][0] = mfma16(a, b2[0][kf], a2[mf2][0]);
            a2[mf2][1] = mfma16(a, b2[1][kf], a2[mf2][1]);
        }
    }

    // ---- store confi pixel-major [b][y][x][28] fp32
#pragma unroll
    for (int mf2 = 0; mf2 < 2; ++mf2)
#pragma unroll
        for (int nf2 = 0; nf2 < 2; ++nf2)
#pragma unroll
            for (int r = 0; r < 4; ++r) {
                int o = nf2 * 16 + c;
                int y = y0 + 2 * wid + mf2;
                int x = x0 + g * 4 + r;
                if (o < OC && x < WW && y < HH)
                    confi[(((size_t)b * HH + y) * WW + x) * OC + o] = a2[mf2][nf2][r];
            }
}

// ---------------- rotated-grid bilinear sampling + mean + sigmoid ----------------
__global__ void __launch_bounds__(256)
sample_kernel(const float* __restrict__ confi, const float* __restrict__ boxes,
              float* __restrict__ out)
{
    const int tid = threadIdx.x;
    const int lb  = tid >> 5;
    const int k   = tid & 31;
    const int box = blockIdx.x * 8 + lb;
    const int b   = box >> 9;
    const int n   = box & 511;

    const float* b5 = boxes + ((size_t)b * NBOX + n) * 5;
    float xg = b5[0], yg = b5[1], wg = b5[2], lg = b5[3], rg = b5[4];
    float cr = cosf(rg), sr = sinf(rg);

    float samp = 0.f;
    if (k < OC) {
        int i = k / 7, j = k - 7 * i;
        float xx = (-0.5f + (float)i * (1.0f / 3.0f)) * wg;
        float yy = (-0.5f + (float)j * (1.0f / 6.0f)) * lg;
        float px = xx * cr + yy * sr + xg;
        float py = yy * cr - xx * sr + yg;
        float fx = px * ((float)WW / (float)(WW - 1)) - 0.5f;
        float fy = py * ((float)HH / (float)(HH - 1)) - 0.5f;
        float x0f = floorf(fx), y0f = floorf(fy);
        float wx = fx - x0f, wy = fy - y0f;
        int xi = (int)x0f, yi = (int)y0f;

        float v00 = 0.f, v10 = 0.f, v01 = 0.f, v11 = 0.f;
        bool okx0 = (xi >= 0)     && (xi <= WW - 1);
        bool okx1 = (xi + 1 >= 0) && (xi + 1 <= WW - 1);
        bool oky0 = (yi >= 0)     && (yi <= HH - 1);
        bool oky1 = (yi + 1 >= 0) && (yi + 1 <= HH - 1);
        if (okx0 && oky0) v00 = confi[(((size_t)b * HH + yi)     * WW + xi)     * OC + k];
        if (okx1 && oky0) v10 = confi[(((size_t)b * HH + yi)     * WW + xi + 1) * OC + k];
        if (okx0 && oky1) v01 = confi[(((size_t)b * HH + yi + 1) * WW + xi)     * OC + k];
        if (okx1 && oky1) v11 = confi[(((size_t)b * HH + yi + 1) * WW + xi + 1) * OC + k];
        samp = v00 * (1.f - wx) * (1.f - wy) + v10 * wx * (1.f - wy)
             + v01 * (1.f - wx) * wy         + v11 * wx * wy;
    }
#pragma unroll
    for (int m = 16; m >= 1; m >>= 1) samp += __shfl_xor(samp, m, 64);

    if (k == 0) {
        float conf = samp * (1.0f / (float)OC);
        out[box] = 1.f / (1.f + expf(-conf));
    }
}

// ---------------- launch ----------------
extern "C" void kernel_launch(void* const* d_in, const int* in_sizes, int n_in,
                              void* d_out, int out_size, void* d_ws, size_t ws_size,
                              hipStream_t stream)
{
    const float* feat  = (const float*)d_in[0];
    const float* w1    = (const float*)d_in[1];
    const float* gamma = (const float*)d_in[2];
    const float* beta  = (const float*)d_in[3];
    const float* rmean = (const float*)d_in[4];
    const float* rvar  = (const float*)d_in[5];
    const float* w2    = (const float*)d_in[6];
    const float* boxes = (const float*)d_in[7];
    float* out = (float*)d_out;

    float* confi = (float*)d_ws;  // [4][376][376][28] fp32 = 63,336,448 B
    unsigned short* w1p = (unsigned short*)((char*)d_ws + 63336448);   // 147456 bf16
    unsigned short* w2p = w1p + 147456;                                 // 4096 bf16
    float* bnsc = (float*)((char*)d_ws + 63336448 + 294912 + 8192);
    float* bnsh = bnsc + CI;

    prep_kernel<<<576, 256, 0, stream>>>(w1, gamma, beta, rmean, rvar, w2,
                                         w1p, w2p, bnsc, bnsh);

    dim3 grid(24, 24, NB);   // x-tiles, y-tiles, batch
    conv_mfma<<<grid, 512, 0, stream>>>(feat, w1p, bnsc, bnsh, w2p, confi);

    sample_kernel<<<NB * NBOX / 8, 256, 0, stream>>>(confi, boxes, out);
}

// Round 3
// 262.829 us; speedup vs baseline: 9.5745x; 1.4481x over previous
//
#include <hip/hip_runtime.h>
#include <math.h>

#define NB   4
#define NBOX 512
#define CI   128
#define HH   376
#define WW   376
#define OC   28
#define HW   (HH * WW)   // 141376

typedef short short8  __attribute__((ext_vector_type(8)));
typedef __bf16 bf16x8 __attribute__((ext_vector_type(8)));
typedef float f32x16  __attribute__((ext_vector_type(16)));
typedef unsigned uint4v __attribute__((ext_vector_type(4)));

typedef const __attribute__((address_space(1))) void gas_void;
typedef __attribute__((address_space(3))) void las_void;

__device__ inline unsigned short f2bf(float f) {
    unsigned u = __builtin_bit_cast(unsigned, f);
    u = u + 0x7fffu + ((u >> 16) & 1u);   // RNE
    return (unsigned short)(u >> 16);
}

__device__ inline unsigned cvtpk_bf16(float lo, float hi) {
    unsigned r;
    asm("v_cvt_pk_bf16_f32 %0, %1, %2" : "=v"(r) : "v"(lo), "v"(hi));
    return r;
}

__device__ inline f32x16 mfma32(short8 a, short8 b, f32x16 c) {
    return __builtin_amdgcn_mfma_f32_32x32x16_bf16(
        __builtin_bit_cast(bf16x8, a), __builtin_bit_cast(bf16x8, b), c, 0, 0, 0);
}

// ================= prep: weights / BN / zero-slot =================
// w1p layout: [chunk=8][co=128][tap=9][slot s'][8 ci], s' = s ^ ((co>>2)&1)
__global__ void __launch_bounds__(256)
prep_kernel(const float* __restrict__ w1, const float* __restrict__ gamma,
            const float* __restrict__ beta, const float* __restrict__ rmean,
            const float* __restrict__ rvar, const float* __restrict__ w2,
            unsigned short* __restrict__ w1p, unsigned short* __restrict__ w2pB,
            float* __restrict__ bnsc, float* __restrict__ bnsh,
            unsigned short* __restrict__ zbuf)
{
    int idx = blockIdx.x * 256 + threadIdx.x;
    if (idx < 8 * 128 * 9 * 16) {          // 147456
        int e    = idx & 7;
        int sp   = (idx >> 3) & 1;
        int t9   = idx >> 4;               // chunk*1152 + co*9 + tap
        int tap  = t9 % 9;
        int t2   = t9 / 9;                 // chunk*128 + co
        int co   = t2 & 127;
        int chnk = t2 >> 7;
        int s    = sp ^ ((co >> 2) & 1);
        int ci   = chnk * 16 + s * 8 + e;
        w1p[idx] = f2bf(w1[((size_t)co * CI + ci) * 9 + tap]);
    }
    if (idx < 32 * 128) {                  // w2pB [32 o][128 co]
        int o = idx >> 7, k = idx & 127;
        w2pB[idx] = (o < OC) ? f2bf(w2[o * CI + k]) : (unsigned short)0;
    }
    if (idx < CI) {
        float rs = rsqrtf(rvar[idx] + 1e-3f);
        bnsc[idx] = gamma[idx] * rs;
        bnsh[idx] = beta[idx] - rmean[idx] * gamma[idx] * rs;
    }
    if (idx < 128) zbuf[idx] = 0;
}

// ================= prepass: feat [b][ci][y][x] f32 -> featp [b][y][x][128] bf16 =================
__global__ void __launch_bounds__(256)
prepass_kernel(const float* __restrict__ feat, unsigned short* __restrict__ featp)
{
    __shared__ unsigned short xl[64 * 136];
    const int t  = threadIdx.x;
    const int bb = blockIdx.x;                 // 4 * 2209
    const int b  = bb / 2209;
    const int s0 = (bb - b * 2209) * 64;

    const int pxq = t & 15;
    const int cib = t >> 4;
#pragma unroll
    for (int it = 0; it < 8; ++it) {
        int ci = it * 16 + cib;
        float4 v = *(const float4*)(feat + ((size_t)(b * CI + ci)) * HW + s0 + pxq * 4);
#pragma unroll
        for (int j = 0; j < 4; ++j)
            xl[(pxq * 4 + j) * 136 + ci] = f2bf((&v.x)[j]);
    }
    __syncthreads();
#pragma unroll
    for (int it = 0; it < 4; ++it) {
        int n  = it * 256 + t;                 // 0..1023
        int px = n >> 4, cs = n & 15;
        short8 v = *(const short8*)(xl + px * 136 + cs * 8);
        *(short8*)(featp + ((size_t)b * HW + s0 + px) * 128 + cs * 8) = v;
    }
}

// ================= fused conv: 3x3 MFMA + BN + ReLU + 1x1 MFMA =================
// block = 256 thr (4 waves), tile 16x16 px x 128 co. Wave w: local rows [4w,4w+4).
// 32x32x16 MFMA, swapped operands: A=weights(rows=co), B=feat(cols=px) -> C[co][px], px per-lane.
__global__ void __launch_bounds__(256, 2)
conv_mfma(const unsigned short* __restrict__ featp,
          const unsigned short* __restrict__ w1p,
          const float* __restrict__ bnsc, const float* __restrict__ bnsh,
          const unsigned short* __restrict__ w2pB,
          const unsigned short* __restrict__ zbuf,
          float* __restrict__ confi)
{
    __shared__ unsigned short sm[24064];   // featl 704 slots (11264 B) + wl 2304 slots (36864 B)
    unsigned short* featl = sm;
    unsigned short* wl    = sm + 5632;

    const int tid  = threadIdx.x;
    const int w    = tid >> 6;
    const int lane = tid & 63;
    const int l31  = lane & 31;
    const int h    = lane >> 5;
    const int x0   = blockIdx.x * 16;
    const int y0   = blockIdx.y * 16;
    const int b    = blockIdx.z;

    // ---- staging source pointers (featl: 11 issues of 64 x 16B) ----
    const unsigned short* fsrc[3];
#pragma unroll
    for (int j = 0; j < 3; ++j) {
        int i  = w + 4 * j;
        int L  = i * 64 + lane;
        int px = L >> 1, s = L & 1;
        int r  = px / 18, cc = px - r * 18;
        int gy = y0 + r - 1, gx = x0 + cc - 1;
        bool ok = (px < 324) && ((unsigned)gy < HH) && ((unsigned)gx < WW);
        int sp = s ^ ((px >> 2) & 1);      // pre-swizzled source slot
        fsrc[j] = ok ? (featp + (((size_t)b * HW + (size_t)gy * WW + gx) * 128) + sp * 8)
                     : (zbuf + sp * 8);
    }

    // ---- per-lane read bases ----
    int pxb[2];
#pragma unroll
    for (int pf = 0; pf < 2; ++pf)
        pxb[pf] = (w * 4 + pf * 2 + (l31 >> 4)) * 18 + (l31 & 15);
    int slA[4];
#pragma unroll
    for (int nf = 0; nf < 4; ++nf) {
        int co = nf * 32 + l31;
        slA[nf] = co * 18 + (h ^ ((co >> 2) & 1));
    }

    f32x16 acc[4][2];
#pragma unroll
    for (int nf = 0; nf < 4; ++nf)
#pragma unroll
        for (int pf = 0; pf < 2; ++pf)
#pragma unroll
            for (int e = 0; e < 16; ++e) acc[nf][pf][e] = 0.f;

    for (int chunk = 0; chunk < 8; ++chunk) {
        __syncthreads();
        // stage feat halo (16 ci): global_load_lds, 16B/lane, linear dest
#pragma unroll
        for (int j = 0; j < 3; ++j) {
            int i = w + 4 * j;
            if (i < 11)
                __builtin_amdgcn_global_load_lds(
                    (gas_void*)(fsrc[j] + chunk * 16),
                    (las_void*)(featl + i * 512), 16, 0, 0);
        }
        // stage weights chunk (128co x 9tap x 16ci, pre-swizzled linear)
#pragma unroll
        for (int j = 0; j < 9; ++j) {
            int i = w * 9 + j;
            __builtin_amdgcn_global_load_lds(
                (gas_void*)(w1p + (size_t)chunk * 18432 + (i * 64 + lane) * 8),
                (las_void*)(wl + i * 512), 16, 0, 0);
        }
        __syncthreads();

#pragma unroll
        for (int tap = 0; tap < 9; ++tap) {
            const int dy = tap / 3, dx = tap - 3 * (tap / 3);
            short8 bfv[2], afv[4];
#pragma unroll
            for (int pf = 0; pf < 2; ++pf) {
                int pxl = pxb[pf] + dy * 18 + dx;
                int sl  = h ^ ((pxl >> 2) & 1);
                bfv[pf] = *(const short8*)(featl + pxl * 16 + sl * 8);
            }
#pragma unroll
            for (int nf = 0; nf < 4; ++nf)
                afv[nf] = *(const short8*)(wl + slA[nf] * 8 + tap * 16);
#pragma unroll
            for (int nf = 0; nf < 4; ++nf)
#pragma unroll
                for (int pf = 0; pf < 2; ++pf)
                    acc[nf][pf] = mfma32(afv[nf], bfv[pf], acc[nf][pf]);
        }
    }

    // ---- BN + ReLU (co = 32nf + (reg&3) + 8q + 4h) ----
#pragma unroll
    for (int nf = 0; nf < 4; ++nf)
#pragma unroll
        for (int q = 0; q < 4; ++q) {
            float4 s4 = *(const float4*)(bnsc + nf * 32 + q * 8 + 4 * h);
            float4 t4 = *(const float4*)(bnsh + nf * 32 + q * 8 + 4 * h);
#pragma unroll
            for (int r = 0; r < 4; ++r)
#pragma unroll
                for (int pf = 0; pf < 2; ++pf)
                    acc[nf][pf][q * 4 + r] =
                        fmaxf(acc[nf][pf][q * 4 + r] * (&s4.x)[r] + (&t4.x)[r], 0.f);
        }

    // ---- 1x1 conv fully in-register: pack acc -> bf16 A-frags (cvt_pk + half-swap) ----
#pragma unroll
    for (int pf = 0; pf < 2; ++pf) {
        f32x16 o2;
#pragma unroll
        for (int e = 0; e < 16; ++e) o2[e] = 0.f;
#pragma unroll
        for (int nf = 0; nf < 4; ++nf) {
#pragma unroll
            for (int half = 0; half < 2; ++half) {
                const int qa = half * 2, qb = half * 2 + 1;
                unsigned A0 = cvtpk_bf16(acc[nf][pf][qa * 4 + 0], acc[nf][pf][qa * 4 + 1]);
                unsigned A1 = cvtpk_bf16(acc[nf][pf][qa * 4 + 2], acc[nf][pf][qa * 4 + 3]);
                unsigned B0 = cvtpk_bf16(acc[nf][pf][qb * 4 + 0], acc[nf][pf][qb * 4 + 1]);
                unsigned B1 = cvtpk_bf16(acc[nf][pf][qb * 4 + 2], acc[nf][pf][qb * 4 + 3]);
                unsigned sA0 = (unsigned)__shfl_xor((int)A0, 32);
                unsigned sA1 = (unsigned)__shfl_xor((int)A1, 32);
                unsigned sB0 = (unsigned)__shfl_xor((int)B0, 32);
                unsigned sB1 = (unsigned)__shfl_xor((int)B1, 32);
                uint4v uv;
                uv[0] = h ? sB0 : A0;      // k = 8h+0,1
                uv[1] = h ? sB1 : A1;      // k = 8h+2,3
                uv[2] = h ? B0  : sA0;     // k = 8h+4,5
                uv[3] = h ? B1  : sA1;     // k = 8h+6,7
                short8 a2 = __builtin_bit_cast(short8, uv);
                int ks = nf * 2 + half;
                short8 wfv = *(const short8*)(w2pB + l31 * 128 + ks * 16 + h * 8);
                o2 = mfma32(a2, wfv, o2);
            }
        }
        // store: lane holds o = l31, px per-reg
#pragma unroll
        for (int reg = 0; reg < 16; ++reg) {
            int row = (reg & 3) + 8 * (reg >> 2) + 4 * h;
            int pxl = w * 64 + pf * 32 + row;
            int y = y0 + (pxl >> 4), x = x0 + (pxl & 15);
            if (l31 < OC && x < WW && y < HH)
                confi[(((size_t)b * HH + y) * WW + x) * OC + l31] = o2[reg];
        }
    }
}

// ================= rotated-grid bilinear sampling + mean + sigmoid =================
__global__ void __launch_bounds__(256)
sample_kernel(const float* __restrict__ confi, const float* __restrict__ boxes,
              float* __restrict__ out)
{
    const int tid = threadIdx.x;
    const int lb  = tid >> 5;
    const int k   = tid & 31;
    const int box = blockIdx.x * 8 + lb;
    const int b   = box >> 9;
    const int n   = box & 511;

    const float* b5 = boxes + ((size_t)b * NBOX + n) * 5;
    float xg = b5[0], yg = b5[1], wg = b5[2], lg = b5[3], rg = b5[4];
    float cr = cosf(rg), sr = sinf(rg);

    float samp = 0.f;
    if (k < OC) {
        int i = k / 7, j = k - 7 * i;
        float xx = (-0.5f + (float)i * (1.0f / 3.0f)) * wg;
        float yy = (-0.5f + (float)j * (1.0f / 6.0f)) * lg;
        float px = xx * cr + yy * sr + xg;
        float py = yy * cr - xx * sr + yg;
        float fx = px * ((float)WW / (float)(WW - 1)) - 0.5f;
        float fy = py * ((float)HH / (float)(HH - 1)) - 0.5f;
        float x0f = floorf(fx), y0f = floorf(fy);
        float wx = fx - x0f, wy = fy - y0f;
        int xi = (int)x0f, yi = (int)y0f;

        float v00 = 0.f, v10 = 0.f, v01 = 0.f, v11 = 0.f;
        bool okx0 = (xi >= 0)     && (xi <= WW - 1);
        bool okx1 = (xi + 1 >= 0) && (xi + 1 <= WW - 1);
        bool oky0 = (yi >= 0)     && (yi <= HH - 1);
        bool oky1 = (yi + 1 >= 0) && (yi + 1 <= HH - 1);
        if (okx0 && oky0) v00 = confi[(((size_t)b * HH + yi)     * WW + xi)     * OC + k];
        if (okx1 && oky0) v10 = confi[(((size_t)b * HH + yi)     * WW + xi + 1) * OC + k];
        if (okx0 && oky1) v01 = confi[(((size_t)b * HH + yi + 1) * WW + xi)     * OC + k];
        if (okx1 && oky1) v11 = confi[(((size_t)b * HH + yi + 1) * WW + xi + 1) * OC + k];
        samp = v00 * (1.f - wx) * (1.f - wy) + v10 * wx * (1.f - wy)
             + v01 * (1.f - wx) * wy         + v11 * wx * wy;
    }
#pragma unroll
    for (int m = 16; m >= 1; m >>= 1) samp += __shfl_xor(samp, m, 64);

    if (k == 0) {
        float conf = samp * (1.0f / (float)OC);
        out[box] = 1.f / (1.f + expf(-conf));
    }
}

// ================= launch =================
extern "C" void kernel_launch(void* const* d_in, const int* in_sizes, int n_in,
                              void* d_out, int out_size, void* d_ws, size_t ws_size,
                              hipStream_t stream)
{
    const float* feat  = (const float*)d_in[0];
    const float* w1    = (const float*)d_in[1];
    const float* gamma = (const float*)d_in[2];
    const float* beta  = (const float*)d_in[3];
    const float* rmean = (const float*)d_in[4];
    const float* rvar  = (const float*)d_in[5];
    const float* w2    = (const float*)d_in[6];
    const float* boxes = (const float*)d_in[7];
    float* out = (float*)d_out;

    char* ws = (char*)d_ws;
    float*          confi = (float*)ws;                              // 63,336,448 B
    unsigned short* featp = (unsigned short*)(ws + 63336448);        // 144,769,024 B
    unsigned short* w1p   = (unsigned short*)(ws + 208105472);       // 294,912 B
    unsigned short* w2pB  = (unsigned short*)(ws + 208400384);       // 8,192 B
    float*          bnsc  = (float*)(ws + 208408576);                // 512 B
    float*          bnsh  = (float*)(ws + 208409088);                // 512 B
    unsigned short* zbuf  = (unsigned short*)(ws + 208409600);       // 256 B

    prep_kernel<<<576, 256, 0, stream>>>(w1, gamma, beta, rmean, rvar, w2,
                                         w1p, w2pB, bnsc, bnsh, zbuf);

    prepass_kernel<<<NB * 2209, 256, 0, stream>>>(feat, featp);

    dim3 grid(24, 24, NB);
    conv_mfma<<<grid, 256, 0, stream>>>(featp, w1p, bnsc, bnsh, w2pB, zbuf, confi);

    sample_kernel<<<NB * NBOX / 8, 256, 0, stream>>>(confi, boxes, out);
}